// Round 2
// baseline (433.402 us; speedup 1.0000x reference)
//
#include <hip/hip_runtime.h>

// Hierarchy: B0=8, B1=16, B2=16; BATCH=32768.
// out[b, (a0*16+a1)*16 + a2] =
//   cumprod(dc0[b])[a0] * cumprod_grp16(dc1[b])[a0,a1] * cumprod_grp16(dc2[b])[a0*16+a1, a2]
//
// Wave-autonomous layout: block = 512 threads = 8 waves = 1 row per iteration.
// Wave w owns a0 = w (16 sibling groups, 4 lanes per group).
// Persistent grid-stride loop (grid=4096, ~8 rows/block) with next-row
// prefetch of dc2/dc1 so HBM latency hides under the shuffle/scan chain.
// Nontemporal load/store on the two streaming 268 MB arrays (no reuse).
// NOTE: __builtin_nontemporal_* requires a clang ext_vector_type, not
// HIP's float4 struct — hence fx4 below.

#define NB0 8
#define NB1 16
#define NB2 16
#define GROUPS (NB0 * NB1)      // 128 groups of 16 leaves
#define ROW_LEN (GROUPS * NB2)  // 2048
#define GRID 4096

typedef float fx4 __attribute__((ext_vector_type(4)));

__global__ __launch_bounds__(512)
void det_prob_kernel(const float* __restrict__ dc0,
                     const float* __restrict__ dc1,
                     const float* __restrict__ dc2,
                     float* __restrict__ out,
                     int batch)
{
    const int t    = threadIdx.x;
    const int wave = t >> 6;   // == a0 for this wave
    const int lane = t & 63;
    const int j    = lane & 3; // position within the group-of-16's quad
    const int g    = lane >> 2; // a1 (group index within this wave's slab)

    const int stride = gridDim.x;
    int row = blockIdx.x;
    if (row >= batch) return;

    // ---- Prefetch first row: dc2 vec4 (streaming) + dc1 value ----
    fx4 x = __builtin_nontemporal_load(
        reinterpret_cast<const fx4*>(dc2 + (size_t)row * ROW_LEN) + t);
    float d1 = dc1[(size_t)row * GROUPS + (size_t)wave * NB1 + g];

    while (true) {
        const int nrow = row + stride;

        // ---- Issue next row's loads before touching this row's data ----
        fx4   xn  = x;
        float d1n = d1;
        if (nrow < batch) {
            xn = __builtin_nontemporal_load(
                reinterpret_cast<const fx4*>(dc2 + (size_t)nrow * ROW_LEN) + t);
            d1n = dc1[(size_t)nrow * GROUPS + (size_t)wave * NB1 + g];
        }

        // ---- c0 = cumprod(dc0[row])[a0]; block-uniform addr -> scalar loads ----
        float c0 = 1.0f;
        #pragma unroll
        for (int k = 0; k < NB0; ++k) {
            float v = dc0[(size_t)row * NB0 + k];
            if (k <= wave) c0 *= v;
        }

        // Inclusive scan of d1 across the 16 groups via lane-scan with
        // quad-sized steps (all 4 lanes of a quad hold the same value).
        float scan = d1;
        #pragma unroll
        for (int off = 4; off <= 32; off <<= 1) {
            float u = __shfl_up(scan, off, 64);
            if (lane >= off) scan *= u;
        }
        const float prefix = c0 * scan;  // c0 * cumprod(dc1 group)[a1], inclusive

        // ---- local cumprod of the 4 dc2 elements ----
        const float y0 = x.x;
        const float y1 = y0 * x.y;
        const float y2 = y1 * x.z;
        const float y3 = y2 * x.w;

        // quad-level exclusive prefix of the per-lane totals
        const int qbase = lane & ~3;
        const float t0 = __shfl(y3, qbase + 0, 64);
        const float t1 = __shfl(y3, qbase + 1, 64);
        const float t2 = __shfl(y3, qbase + 2, 64);

        float p = prefix;
        if (j > 0) p *= t0;
        if (j > 1) p *= t1;
        if (j > 2) p *= t2;

        fx4 o;
        o.x = y0 * p;
        o.y = y1 * p;
        o.z = y2 * p;
        o.w = y3 * p;
        __builtin_nontemporal_store(
            o, reinterpret_cast<fx4*>(out + (size_t)row * ROW_LEN) + t);

        if (nrow >= batch) break;
        row = nrow;
        x = xn;
        d1 = d1n;
    }
}

extern "C" void kernel_launch(void* const* d_in, const int* in_sizes, int n_in,
                              void* d_out, int out_size, void* d_ws, size_t ws_size,
                              hipStream_t stream) {
    const float* dc0 = (const float*)d_in[0];
    const float* dc1 = (const float*)d_in[1];
    const float* dc2 = (const float*)d_in[2];
    float* out = (float*)d_out;

    const int batch = in_sizes[0] / NB0;  // 32768
    int grid = GRID;
    if (grid > batch) grid = batch;
    det_prob_kernel<<<grid, 512, 0, stream>>>(dc0, dc1, dc2, out, batch);
}